// Round 5
// baseline (258.465 us; speedup 1.0000x reference)
//
#include <hip/hip_runtime.h>
#include <hip/hip_bf16.h>

typedef __bf16 v8bf __attribute__((ext_vector_type(8)));
typedef float v4f __attribute__((ext_vector_type(4)));

#define GBL_AS(p) ((const __attribute__((address_space(1))) unsigned int*)(p))
#define LDS_AS(p) ((__attribute__((address_space(3))) unsigned int*)(p))

// s_waitcnt immediates: lgkmcnt=15 (no wait) bits[11:8], expcnt=7 bits[6:4],
// vmcnt low bits[3:0].
#define WAIT_VM6() __builtin_amdgcn_s_waitcnt(0x0F76)  // vmcnt(6)
#define WAIT_VM0() __builtin_amdgcn_s_waitcnt(0x0F70)  // vmcnt(0)

// ---------------- fp32 -> bf16 cast (x) ----------------
__global__ void cast_f32_bf16(const float* __restrict__ src,
                              __hip_bfloat16* __restrict__ dst, int n) {
  int i = (blockIdx.x * 256 + threadIdx.x) * 4;
  if (i >= n) return;
  float4 f = *(const float4*)(src + i);
  union { __hip_bfloat16 h[4]; uint2 u; } pk;
  pk.h[0] = __float2bfloat16(f.x);
  pk.h[1] = __float2bfloat16(f.y);
  pk.h[2] = __float2bfloat16(f.z);
  pk.h[3] = __float2bfloat16(f.w);
  *(uint2*)(dst + i) = pk.u;
}

// ---------------- fp32 -> bf16 cast, 3 weight tensors ----------------
__global__ void cast_w3(const float* __restrict__ a, const float* __restrict__ b,
                        const float* __restrict__ c, __hip_bfloat16* __restrict__ dst) {
  int seg = blockIdx.x >> 10;
  const float* src = seg == 0 ? a : (seg == 1 ? b : c);
  int i = ((blockIdx.x & 1023) * 256 + threadIdx.x) * 4;
  float4 f = *(const float4*)(src + i);
  union { __hip_bfloat16 h[4]; uint2 u; } pk;
  pk.h[0] = __float2bfloat16(f.x);
  pk.h[1] = __float2bfloat16(f.y);
  pk.h[2] = __float2bfloat16(f.z);
  pk.h[3] = __float2bfloat16(f.w);
  *(uint2*)(dst + seg * 1048576 + i) = pk.u;
}

// ================= shared 256x128 tile machinery =================
// 4 waves of 128x64 (acc[8][4]); per K-step 6 global_load_lds (A 16KB + B 8KB),
// triple LDS buffer, counted vmcnt(6). LDS XOR-swizzle: 16B chunk (row r,
// col-chunk c in 0..3) at slot c ^ ((r>>1)&3), realized via permuted per-lane
// GLOBAL source (DMA dest linear); same XOR folded into read bases.

// ---------------- projection GEMM (r1-proven, unchanged: 68.3us) ----------------
__global__ __launch_bounds__(256, 2)
void gemm_proj(const __hip_bfloat16* __restrict__ A, int lda,
               const __hip_bfloat16* __restrict__ B, long sBb, int ldb,
               __hip_bfloat16* __restrict__ C, long sCb, int ldc,
               float scale, __hip_bfloat16* __restrict__ vTp) {
  const int tid = threadIdx.x;
  const int l = tid & 63, w = tid >> 6;
  const int z  = blockIdx.x >> 3;
  const int nb = (blockIdx.x & 7) << 7;   // N-tile: 128 wide
  const int mb = blockIdx.y << 8;         // M-tile: 256 tall

  B += (long)z * sBb;

  __shared__ alignas(16) __hip_bfloat16 As[3][256 * 32];   // 16KB per buf
  __shared__ alignas(16) __hip_bfloat16 Bs[3][128 * 32];   // 8KB per buf

  v4f acc[8][4] = {};
  const int wm = (w >> 1) << 7;   // 0 or 128
  const int wn = (w & 1) << 6;    // 0 or 64

  const int qa0 = 0 * 256 + w * 64 + l, ra0 = qa0 >> 2;
  const int qa1 = 1 * 256 + w * 64 + l, ra1 = qa1 >> 2;
  const int qa2 = 2 * 256 + w * 64 + l, ra2 = qa2 >> 2;
  const int qa3 = 3 * 256 + w * 64 + l, ra3 = qa3 >> 2;
  const __hip_bfloat16* sA0 = A + (long)(mb + ra0) * lda + (((qa0 & 3) ^ ((ra0 >> 1) & 3)) << 3);
  const __hip_bfloat16* sA1 = A + (long)(mb + ra1) * lda + (((qa1 & 3) ^ ((ra1 >> 1) & 3)) << 3);
  const __hip_bfloat16* sA2 = A + (long)(mb + ra2) * lda + (((qa2 & 3) ^ ((ra2 >> 1) & 3)) << 3);
  const __hip_bfloat16* sA3 = A + (long)(mb + ra3) * lda + (((qa3 & 3) ^ ((ra3 >> 1) & 3)) << 3);
  const int qb0 = 0 * 256 + w * 64 + l, rb0 = qb0 >> 2;
  const int qb1 = 1 * 256 + w * 64 + l, rb1 = qb1 >> 2;
  const __hip_bfloat16* sB0 = B + (long)(nb + rb0) * ldb + (((qb0 & 3) ^ ((rb0 >> 1) & 3)) << 3);
  const __hip_bfloat16* sB1 = B + (long)(nb + rb1) * ldb + (((qb1 & 3) ^ ((rb1 >> 1) & 3)) << 3);

  const int arow = wm + (l & 15);
  const int ldsA = arow * 32 + ((((l >> 4) ^ ((arow >> 1) & 3))) << 3);
  const int brow = wn + (l & 15);
  const int ldsB = brow * 32 + ((((l >> 4) ^ ((brow >> 1) & 3))) << 3);

#define STAGE_P(K0, BUF) do {                                                   \
    __builtin_amdgcn_global_load_lds(GBL_AS(sA0 + (K0)),                        \
        LDS_AS(&As[BUF][0 * 2048 + w * 512]), 16, 0, 0);                        \
    __builtin_amdgcn_global_load_lds(GBL_AS(sA1 + (K0)),                        \
        LDS_AS(&As[BUF][1 * 2048 + w * 512]), 16, 0, 0);                        \
    __builtin_amdgcn_global_load_lds(GBL_AS(sA2 + (K0)),                        \
        LDS_AS(&As[BUF][2 * 2048 + w * 512]), 16, 0, 0);                        \
    __builtin_amdgcn_global_load_lds(GBL_AS(sA3 + (K0)),                        \
        LDS_AS(&As[BUF][3 * 2048 + w * 512]), 16, 0, 0);                        \
    __builtin_amdgcn_global_load_lds(GBL_AS(sB0 + (K0)),                        \
        LDS_AS(&Bs[BUF][0 * 2048 + w * 512]), 16, 0, 0);                        \
    __builtin_amdgcn_global_load_lds(GBL_AS(sB1 + (K0)),                        \
        LDS_AS(&Bs[BUF][1 * 2048 + w * 512]), 16, 0, 0);                        \
  } while (0)

#define COMPUTE_P(BI) do {                                                      \
    v8bf af[8], bfr[4];                                                         \
    _Pragma("unroll")                                                           \
    for (int i = 0; i < 8; ++i)                                                 \
      af[i]  = *(const v8bf*)(&As[BI][ldsA + i * 512]);                         \
    _Pragma("unroll")                                                           \
    for (int j = 0; j < 4; ++j)                                                 \
      bfr[j] = *(const v8bf*)(&Bs[BI][ldsB + j * 512]);                         \
    _Pragma("unroll")                                                           \
    for (int i = 0; i < 8; ++i)                                                 \
      _Pragma("unroll")                                                         \
      for (int j = 0; j < 4; ++j)                                               \
        acc[i][j] = __builtin_amdgcn_mfma_f32_16x16x32_bf16(af[i], bfr[j],      \
                                                            acc[i][j], 0, 0, 0);\
  } while (0)

#define KITER_P(IT) do {                                                        \
    if constexpr ((IT) < 31) WAIT_VM6(); else WAIT_VM0();                       \
    __builtin_amdgcn_s_barrier();                                               \
    if constexpr ((IT) < 30) STAGE_P((IT) * 32 + 64, ((IT) + 2) % 3);           \
    COMPUTE_P((IT) % 3);                                                        \
  } while (0)

  STAGE_P(0, 0);
  STAGE_P(32, 1);
  KITER_P(0);  KITER_P(1);  KITER_P(2);  KITER_P(3);  KITER_P(4);  KITER_P(5);
  KITER_P(6);  KITER_P(7);  KITER_P(8);  KITER_P(9);  KITER_P(10); KITER_P(11);
  KITER_P(12); KITER_P(13); KITER_P(14); KITER_P(15); KITER_P(16); KITER_P(17);
  KITER_P(18); KITER_P(19); KITER_P(20); KITER_P(21); KITER_P(22); KITER_P(23);
  KITER_P(24); KITER_P(25); KITER_P(26); KITER_P(27); KITER_P(28); KITER_P(29);
  KITER_P(30); KITER_P(31);
#undef KITER_P
#undef COMPUTE_P
#undef STAGE_P

  // epilogue: C/D layout col=lane&15, row=(lane>>4)*4+reg [m89-verified]
  const int col0 = nb + wn + (l & 15);
  const int row0 = mb + wm + ((l >> 4) << 2);
  if (z < 2) {
    __hip_bfloat16* Cz = C + (long)z * sCb;
#pragma unroll
    for (int i = 0; i < 8; ++i)
#pragma unroll
      for (int r = 0; r < 4; ++r) {
        long ro = (long)(row0 + i * 16 + r) * ldc;
#pragma unroll
        for (int j = 0; j < 4; ++j)
          Cz[ro + col0 + j * 16] = __float2bfloat16(acc[i][j][r] * scale);
      }
  } else {
    // V projection: write transposed into vT[b][col][seq], 8B packed stores
    const long b = row0 >> 11;
    const int seq0 = row0 & 2047;
#pragma unroll
    for (int i = 0; i < 8; ++i)
#pragma unroll
      for (int j = 0; j < 4; ++j) {
        union { __hip_bfloat16 h[4]; uint2 u; } pk;
#pragma unroll
        for (int r = 0; r < 4; ++r) pk.h[r] = __float2bfloat16(acc[i][j][r]);
        *(uint2*)(vTp + b * 2097152 + (long)(col0 + j * 16) * 2048 +
                  (seq0 + i * 16)) = pk.u;
      }
  }
}

// ---------------- scores: 256x128 tile (proj geometry) ----------------
// THEORY (r5): per-iter cost is ~fixed (~1700 cyc/block); only MFMA payload
// varies. proj (32 MFMA/iter/wave) = 755 TF vs score's old 128^2 (16) = 277.
// Same body as proj => same rate; triangular 256x128 grid = 288 blocks
// (8 XCD x 36, m-major within XCD). Masked tiles computed+zeroed (+6% FLOPs);
// the stored zeros keep pv's kend-rectangular reads exact.
__global__ __launch_bounds__(256, 2)
void gemm_score(const __hip_bfloat16* __restrict__ A, long sAb,
                const __hip_bfloat16* __restrict__ B, long sBb,
                __hip_bfloat16* __restrict__ C, long sCb,
                float scale, float* __restrict__ sums) {
  const int tid = threadIdx.x;
  const int l = tid & 63, w = tid >> 6;
  const int id = blockIdx.x;            // 288 = 8 XCD x 36
  const int wk = (id & 7) * 36 + (id >> 3);
  const int z = wk / 72;
  const int t = wk - z * 72;            // 0..71: m-major over (m2, n<=2*m2+1)
  int m2 = (int)(__builtin_sqrtf((float)t));
  while ((m2 + 1) * (m2 + 2) <= t) ++m2;
  while (m2 * (m2 + 1) > t) --m2;
  const int mb = m2 << 8;
  const int nb = (t - m2 * (m2 + 1)) << 7;

  const __hip_bfloat16* Az = A + (long)z * sAb;   // q, ld 1024
  const __hip_bfloat16* Bz = B + (long)z * sBb;   // k, ld 1024

  __shared__ alignas(16) __hip_bfloat16 As[3][256 * 32];
  __shared__ alignas(16) __hip_bfloat16 Bs[3][128 * 32];

  v4f acc[8][4] = {};
  const int wm = (w >> 1) << 7;
  const int wn = (w & 1) << 6;

  const int qa0 = 0 * 256 + w * 64 + l, ra0 = qa0 >> 2;
  const int qa1 = 1 * 256 + w * 64 + l, ra1 = qa1 >> 2;
  const int qa2 = 2 * 256 + w * 64 + l, ra2 = qa2 >> 2;
  const int qa3 = 3 * 256 + w * 64 + l, ra3 = qa3 >> 2;
  const __hip_bfloat16* sA0 = Az + (long)(mb + ra0) * 1024 + (((qa0 & 3) ^ ((ra0 >> 1) & 3)) << 3);
  const __hip_bfloat16* sA1 = Az + (long)(mb + ra1) * 1024 + (((qa1 & 3) ^ ((ra1 >> 1) & 3)) << 3);
  const __hip_bfloat16* sA2 = Az + (long)(mb + ra2) * 1024 + (((qa2 & 3) ^ ((ra2 >> 1) & 3)) << 3);
  const __hip_bfloat16* sA3 = Az + (long)(mb + ra3) * 1024 + (((qa3 & 3) ^ ((ra3 >> 1) & 3)) << 3);
  const int qb0 = 0 * 256 + w * 64 + l, rb0 = qb0 >> 2;
  const int qb1 = 1 * 256 + w * 64 + l, rb1 = qb1 >> 2;
  const __hip_bfloat16* sB0 = Bz + (long)(nb + rb0) * 1024 + (((qb0 & 3) ^ ((rb0 >> 1) & 3)) << 3);
  const __hip_bfloat16* sB1 = Bz + (long)(nb + rb1) * 1024 + (((qb1 & 3) ^ ((rb1 >> 1) & 3)) << 3);

  const int arow = wm + (l & 15);
  const int ldsA = arow * 32 + ((((l >> 4) ^ ((arow >> 1) & 3))) << 3);
  const int brow = wn + (l & 15);
  const int ldsB = brow * 32 + ((((l >> 4) ^ ((brow >> 1) & 3))) << 3);

#define STAGE_Q(K0, BUF) do {                                                   \
    __builtin_amdgcn_global_load_lds(GBL_AS(sA0 + (K0)),                        \
        LDS_AS(&As[BUF][0 * 2048 + w * 512]), 16, 0, 0);                        \
    __builtin_amdgcn_global_load_lds(GBL_AS(sA1 + (K0)),                        \
        LDS_AS(&As[BUF][1 * 2048 + w * 512]), 16, 0, 0);                        \
    __builtin_amdgcn_global_load_lds(GBL_AS(sA2 + (K0)),                        \
        LDS_AS(&As[BUF][2 * 2048 + w * 512]), 16, 0, 0);                        \
    __builtin_amdgcn_global_load_lds(GBL_AS(sA3 + (K0)),                        \
        LDS_AS(&As[BUF][3 * 2048 + w * 512]), 16, 0, 0);                        \
    __builtin_amdgcn_global_load_lds(GBL_AS(sB0 + (K0)),                        \
        LDS_AS(&Bs[BUF][0 * 2048 + w * 512]), 16, 0, 0);                        \
    __builtin_amdgcn_global_load_lds(GBL_AS(sB1 + (K0)),                        \
        LDS_AS(&Bs[BUF][1 * 2048 + w * 512]), 16, 0, 0);                        \
  } while (0)

#define COMPUTE_Q(BI) do {                                                      \
    v8bf af[8], bfr[4];                                                         \
    _Pragma("unroll")                                                           \
    for (int i = 0; i < 8; ++i)                                                 \
      af[i]  = *(const v8bf*)(&As[BI][ldsA + i * 512]);                         \
    _Pragma("unroll")                                                           \
    for (int j = 0; j < 4; ++j)                                                 \
      bfr[j] = *(const v8bf*)(&Bs[BI][ldsB + j * 512]);                         \
    _Pragma("unroll")                                                           \
    for (int i = 0; i < 8; ++i)                                                 \
      _Pragma("unroll")                                                         \
      for (int j = 0; j < 4; ++j)                                               \
        acc[i][j] = __builtin_amdgcn_mfma_f32_16x16x32_bf16(af[i], bfr[j],      \
                                                            acc[i][j], 0, 0, 0);\
  } while (0)

#define KITER_Q(IT) do {                                                        \
    if constexpr ((IT) < 31) WAIT_VM6(); else WAIT_VM0();                       \
    __builtin_amdgcn_s_barrier();                                               \
    if constexpr ((IT) < 30) STAGE_Q((IT) * 32 + 64, ((IT) + 2) % 3);           \
    COMPUTE_Q((IT) % 3);                                                        \
  } while (0)

  STAGE_Q(0, 0);
  STAGE_Q(32, 1);
  KITER_Q(0);  KITER_Q(1);  KITER_Q(2);  KITER_Q(3);  KITER_Q(4);  KITER_Q(5);
  KITER_Q(6);  KITER_Q(7);  KITER_Q(8);  KITER_Q(9);  KITER_Q(10); KITER_Q(11);
  KITER_Q(12); KITER_Q(13); KITER_Q(14); KITER_Q(15); KITER_Q(16); KITER_Q(17);
  KITER_Q(18); KITER_Q(19); KITER_Q(20); KITER_Q(21); KITER_Q(22); KITER_Q(23);
  KITER_Q(24); KITER_Q(25); KITER_Q(26); KITER_Q(27); KITER_Q(28); KITER_Q(29);
  KITER_Q(30); KITER_Q(31);
#undef KITER_Q
#undef COMPUTE_Q
#undef STAGE_Q

  // epilogue: exp + causal mask + bf16 store + fused row-sum atomics
  __hip_bfloat16* Cz = C + (long)z * sCb;
  float* srow = sums + z * 2048;
  const int col0 = nb + wn + (l & 15);
  const int row0 = mb + wm + ((l >> 4) << 2);
#pragma unroll
  for (int i = 0; i < 8; ++i)
#pragma unroll
    for (int r = 0; r < 4; ++r) {
      const int m = row0 + i * 16 + r;
      const long ro = (long)m * 2048;
      float sp = 0.f;
#pragma unroll
      for (int j = 0; j < 4; ++j) {
        const int n = col0 + j * 16;
        float pv = (n <= m) ? __expf(acc[i][j][r] * scale) : 0.0f;
        sp += pv;
        Cz[ro + n] = __float2bfloat16(pv);
      }
      sp += __shfl_xor(sp, 1);
      sp += __shfl_xor(sp, 2);
      sp += __shfl_xor(sp, 4);
      sp += __shfl_xor(sp, 8);
      if ((l & 15) == 0) atomicAdd(&srow[m], sp);
    }
}

// ---------------- PV: 256x128 tile, dynamic causal K ----------------
// Same geometry/theory as score. 256 blocks = 1/CU (8 XCD x 32); rolling
// 3-buffer pipeline (r1-proven form widened to 6 loads / vmcnt(6));
// kend = 256*(m2+1); plain fp32 stores (no split-K, no memset).
__global__ __launch_bounds__(256, 2)
void gemm_pv(const __hip_bfloat16* __restrict__ A, long sAb, int lda,
             const __hip_bfloat16* __restrict__ B, long sBb, int ldb,
             float* __restrict__ C, long sCb, int ldc,
             const float* __restrict__ sums) {
  const int tid = threadIdx.x;
  const int l = tid & 63, w = tid >> 6;
  const int id = blockIdx.x;            // 256 = 8 XCD x 32
  const int wk = (id & 7) * 32 + (id >> 3);
  const int z = wk >> 6;
  const int r6 = wk & 63;
  const int m2 = r6 >> 3, c = r6 & 7;
  const int mb = m2 << 8, nb = c << 7;
  const int kend = (m2 + 1) << 8;

  A += (long)z * sAb;   // P  (lda = 2048)
  B += (long)z * sBb;   // vT (ldb = 2048)

  __shared__ alignas(16) __hip_bfloat16 As[3][256 * 32];
  __shared__ alignas(16) __hip_bfloat16 Bs[3][128 * 32];

  v4f acc[8][4] = {};
  const int wm = (w >> 1) << 7;
  const int wn = (w & 1) << 6;

  const int qa0 = 0 * 256 + w * 64 + l, ra0 = qa0 >> 2;
  const int qa1 = 1 * 256 + w * 64 + l, ra1 = qa1 >> 2;
  const int qa2 = 2 * 256 + w * 64 + l, ra2 = qa2 >> 2;
  const int qa3 = 3 * 256 + w * 64 + l, ra3 = qa3 >> 2;
  const __hip_bfloat16* sA0 = A + (long)(mb + ra0) * lda + (((qa0 & 3) ^ ((ra0 >> 1) & 3)) << 3);
  const __hip_bfloat16* sA1 = A + (long)(mb + ra1) * lda + (((qa1 & 3) ^ ((ra1 >> 1) & 3)) << 3);
  const __hip_bfloat16* sA2 = A + (long)(mb + ra2) * lda + (((qa2 & 3) ^ ((ra2 >> 1) & 3)) << 3);
  const __hip_bfloat16* sA3 = A + (long)(mb + ra3) * lda + (((qa3 & 3) ^ ((ra3 >> 1) & 3)) << 3);
  const int qb0 = 0 * 256 + w * 64 + l, rb0 = qb0 >> 2;
  const int qb1 = 1 * 256 + w * 64 + l, rb1 = qb1 >> 2;
  const __hip_bfloat16* sB0 = B + (long)(nb + rb0) * ldb + (((qb0 & 3) ^ ((rb0 >> 1) & 3)) << 3);
  const __hip_bfloat16* sB1 = B + (long)(nb + rb1) * ldb + (((qb1 & 3) ^ ((rb1 >> 1) & 3)) << 3);

  const int arow = wm + (l & 15);
  const int ldsA = arow * 32 + ((((l >> 4) ^ ((arow >> 1) & 3))) << 3);
  const int brow = wn + (l & 15);
  const int ldsB = brow * 32 + ((((l >> 4) ^ ((brow >> 1) & 3))) << 3);

  auto stage = [&](int k0, int buf) {
    __builtin_amdgcn_global_load_lds(GBL_AS(sA0 + k0),
        LDS_AS(&As[buf][0 * 2048 + w * 512]), 16, 0, 0);
    __builtin_amdgcn_global_load_lds(GBL_AS(sA1 + k0),
        LDS_AS(&As[buf][1 * 2048 + w * 512]), 16, 0, 0);
    __builtin_amdgcn_global_load_lds(GBL_AS(sA2 + k0),
        LDS_AS(&As[buf][2 * 2048 + w * 512]), 16, 0, 0);
    __builtin_amdgcn_global_load_lds(GBL_AS(sA3 + k0),
        LDS_AS(&As[buf][3 * 2048 + w * 512]), 16, 0, 0);
    __builtin_amdgcn_global_load_lds(GBL_AS(sB0 + k0),
        LDS_AS(&Bs[buf][0 * 2048 + w * 512]), 16, 0, 0);
    __builtin_amdgcn_global_load_lds(GBL_AS(sB1 + k0),
        LDS_AS(&Bs[buf][1 * 2048 + w * 512]), 16, 0, 0);
  };
  stage(0, 0);
  if (32 < kend) stage(32, 1);
  int bi = 0;
  for (int k0 = 0; k0 < kend; k0 += 32) {
    if (k0 + 32 < kend) WAIT_VM6(); else WAIT_VM0();
    __builtin_amdgcn_s_barrier();
    if (k0 + 64 < kend) stage(k0 + 64, bi == 0 ? 2 : bi - 1);
    v8bf af[8], bfr[4];
#pragma unroll
    for (int i = 0; i < 8; ++i)
      af[i]  = *(const v8bf*)(&As[bi][ldsA + i * 512]);
#pragma unroll
    for (int j = 0; j < 4; ++j)
      bfr[j] = *(const v8bf*)(&Bs[bi][ldsB + j * 512]);
#pragma unroll
    for (int i = 0; i < 8; ++i)
#pragma unroll
      for (int j = 0; j < 4; ++j)
        acc[i][j] = __builtin_amdgcn_mfma_f32_16x16x32_bf16(af[i], bfr[j], acc[i][j], 0, 0, 0);
    bi = (bi == 2) ? 0 : bi + 1;
  }

  // epilogue: divide by rowsum, fp32 direct stores
  float* Cz = C + (long)z * sCb;
  const float* srow = sums + z * 2048;
  const int col0 = nb + wn + (l & 15);
  const int row0 = mb + wm + ((l >> 4) << 2);
#pragma unroll
  for (int i = 0; i < 8; ++i)
#pragma unroll
    for (int r = 0; r < 4; ++r) {
      const int mr = row0 + i * 16 + r;
      const float sc = 1.0f / srow[mr];
      const long ro = (long)mr * ldc;
#pragma unroll
      for (int j = 0; j < 4; ++j)
        Cz[ro + col0 + j * 16] = acc[i][j][r] * sc;
    }
}

// ---------------- launch ----------------
extern "C" void kernel_launch(void* const* d_in, const int* in_sizes, int n_in,
                              void* d_out, int out_size, void* d_ws, size_t ws_size,
                              hipStream_t stream) {
  const float* x  = (const float*)d_in[0];
  const float* Wq = (const float*)d_in[1];
  const float* Wk = (const float*)d_in[2];
  const float* Wv = (const float*)d_in[3];
  float* out = (float*)d_out;
  char* ws = (char*)d_ws;

  // ws layout (bytes):
  //   qkv bf16 [3][8192][1024]   @ 0          (48 MB; v-slice unused)
  //   vT  bf16 [4][1024][2048]   @ 50331648   (16 MB)
  //   xb  bf16 [8192][1024]      @ 67108864   (16 MB, dead after proj)
  //   Wb  bf16 [3][1024][1024]   @ 83886080   ( 6 MB, dead after proj)
  //   P   bf16 [4][2048][2048]   @ 67108864   (32 MB, overlaps dead xb/Wb)
  //   sums fp32 [8192]           @ 100663296  (32 KB)
  __hip_bfloat16* qkv = (__hip_bfloat16*)ws;
  __hip_bfloat16* vT  = (__hip_bfloat16*)(ws + 50331648);
  __hip_bfloat16* xb  = (__hip_bfloat16*)(ws + 67108864);
  __hip_bfloat16* Wb  = (__hip_bfloat16*)(ws + 83886080);
  __hip_bfloat16* P   = (__hip_bfloat16*)(ws + 67108864);
  float* sums         = (float*)(ws + 100663296);

  hipMemsetAsync(sums, 0, 8192 * sizeof(float), stream);

  cast_f32_bf16<<<8192, 256, 0, stream>>>(x, xb, 8388608);
  cast_w3<<<3072, 256, 0, stream>>>(Wq, Wk, Wv, Wb);

  // qkv projections; z==2 (V) written transposed into vT by the epilogue
  gemm_proj<<<dim3(24, 32, 1), 256, 0, stream>>>(
      xb, 1024, Wb, 1048576L, 1024, qkv, 8388608L, 1024, 1.0f, vT);

  // P = exp((q@k^T)/32) causal, bf16, fused row-sums; 256x128 tiles, 288 blocks
  gemm_score<<<dim3(288, 1, 1), 256, 0, stream>>>(
      qkv, 2097152L, qkv + 8388608, 2097152L,
      P, 4194304L, 0.03125f, sums);

  // out = (P @ vT^T) / rowsum; 256x128 tiles, dynamic K, 256 blocks
  gemm_pv<<<dim3(256, 1, 1), 256, 0, stream>>>(
      P, 4194304L, 2048, vT, 2097152L, 2048,
      out, 2097152L, 1024, sums);
}